// Round 6
// baseline (350.344 us; speedup 1.0000x reference)
//
#include <hip/hip_runtime.h>

typedef float  f32x4  __attribute__((ext_vector_type(4)));
typedef float  f4v    __attribute__((ext_vector_type(4)));
typedef __bf16 bf16x8 __attribute__((ext_vector_type(8)));
typedef __bf16 bf16x4 __attribute__((ext_vector_type(4)));
typedef unsigned short ushort_t;

#define AS1 __attribute__((address_space(1)))
#define AS3 __attribute__((address_space(3)))

static __device__ __forceinline__ void gload_lds16(const void* g, void* l) {
  __builtin_amdgcn_global_load_lds((const AS1 void*)g, (AS3 void*)l, 16, 0, 0);
}

// mish(x) = x * u/(u+2), u = t*(t+2), t = e^x; guard large x.
static __device__ __forceinline__ float mishf(float x) {
  float t = __expf(x);
  float u = t * (t + 2.f);
  float y = x * __fdividef(u, u + 2.f);
  return (x > 15.f) ? x : y;
}

// ---------------- weight cast fp32 -> bf16 (packed layout) ----------------
__global__ __launch_bounds__(256) void castw(
    const float* __restrict__ Wq, const float* __restrict__ Wk,
    const float* __restrict__ Wv, const float* __restrict__ Wp,
    const float* __restrict__ W1, const float* __restrict__ W2,
    __bf16* __restrict__ out)
{
  const int i = (blockIdx.x * 256 + threadIdx.x) * 4;
  const float* src; int off = i;
  if      (i < 65536)  { src = Wq; }
  else if (i < 131072) { src = Wk; off = i - 65536; }
  else if (i < 196608) { src = Wv; off = i - 131072; }
  else if (i < 262144) { src = Wp; off = i - 196608; }
  else if (i < 524288) { src = W1; off = i - 262144; }
  else                 { src = W2; off = i - 524288; }
  const f4v v = *(const f4v*)(src + off);
  bf16x4 o;
  #pragma unroll
  for (int j = 0; j < 4; ++j) o[j] = (__bf16)v[j];
  *(bf16x4*)(out + i) = o;
}

__global__ void packb(const float* __restrict__ a, const float* __restrict__ b,
                      const float* __restrict__ c, float* __restrict__ o) {
  int i = threadIdx.x;  // 768 threads
  o[i] = (i < 256) ? a[i] : (i < 512 ? b[i - 256] : c[i - 512]);
}

// ---------------- LayerNorm row kernel: fp32 in -> bf16 out ----------------
__global__ __launch_bounds__(256) void ln_rows(
    const float* __restrict__ X, const float* __restrict__ g,
    const float* __restrict__ b, __bf16* __restrict__ Y)
{
  const int l = threadIdx.x & 63;
  const size_t row = (size_t)blockIdx.x * 4 + (threadIdx.x >> 6);
  const f4v x = *(const f4v*)(X + row * 256 + l * 4);
  float s = x[0] + x[1] + x[2] + x[3];
  float q = x[0]*x[0] + x[1]*x[1] + x[2]*x[2] + x[3]*x[3];
  #pragma unroll
  for (int d = 1; d < 64; d <<= 1) { s += __shfl_xor(s, d); q += __shfl_xor(q, d); }
  const float mu = s * (1.f / 256.f);
  const float rs = rsqrtf(q * (1.f / 256.f) - mu * mu + 1e-5f);
  const f4v gv = *(const f4v*)(g + l * 4);
  const f4v bv = *(const f4v*)(b + l * 4);
  bf16x4 o;
  #pragma unroll
  for (int j = 0; j < 4; ++j) o[j] = (__bf16)((x[j] - mu) * rs * gv[j] + bv[j]);
  *(bf16x4*)(Y + row * 256 + l * 4) = o;
}

// ---------------- GEMM  C[M, N-cols] = act(A @ Bw^T + bias) (+res) --------
// m97 structure: 128x128 tile, BK=32, 4 waves (2x2, wave tile 64x64),
// gload_lds x4 staging, ~4 blocks/CU. Epilogue: per-wave fp32 LDS strip
// [32][66] (stride 66 dwords -> uniform 2-way write groups, free), two
// 32-row passes, no epilogue barriers; coalesced 16B global stores.
template<int ACT, int RES, int OUTBF>
__global__ __launch_bounds__(256, 2) void gemm_bt(
    const __bf16* __restrict__ A, const __bf16* __restrict__ Bw,
    const float* __restrict__ bias, const float* __restrict__ res,
    void* __restrict__ Cv, int N, int K)
{
  __shared__ union U {
    struct { __bf16 A[2][128][32]; __bf16 B[2][128][32]; } st; // 32 KB
    float ep[4][32 * 66];                                      // 33792 B
  } lds;
  const int tid = threadIdx.x;
  const int l = tid & 63;
  const int w = tid >> 6, wr = w >> 1, wc = w & 1;
  const int mt = blockIdx.x, nt = blockIdx.y;

  const __bf16* ga = A  + (size_t)(mt * 128 + (tid >> 2)) * K + (tid & 3) * 8;
  const __bf16* gb = Bw + (size_t)(nt * 128 + (tid >> 2)) * K + (tid & 3) * 8;

  auto stage = [&](int buf, int kt) {
    const __bf16* a = ga + kt * 32;
    const __bf16* b = gb + kt * 32;
    gload_lds16(a,          &lds.st.A[buf][tid >> 2][(tid & 3) * 8]);
    gload_lds16(a + 64 * K, &lds.st.A[buf][64 + (tid >> 2)][(tid & 3) * 8]);
    gload_lds16(b,          &lds.st.B[buf][tid >> 2][(tid & 3) * 8]);
    gload_lds16(b + 64 * K, &lds.st.B[buf][64 + (tid >> 2)][(tid & 3) * 8]);
  };

  f32x4 acc[4][4] = {};
  const int NK = K >> 5;
  stage(0, 0);
  __syncthreads();
  int cur = 0;
  for (int kt = 0;;) {
    if (kt + 1 < NK) stage(cur ^ 1, kt + 1);
    bf16x8 af[4], bfr[4];
    #pragma unroll
    for (int m = 0; m < 4; ++m)
      af[m] = *(const bf16x8*)&lds.st.A[cur][wr * 64 + m * 16 + (l & 15)][(l >> 4) * 8];
    #pragma unroll
    for (int n = 0; n < 4; ++n)
      bfr[n] = *(const bf16x8*)&lds.st.B[cur][wc * 64 + n * 16 + (l & 15)][(l >> 4) * 8];
    #pragma unroll
    for (int m = 0; m < 4; ++m)
      #pragma unroll
      for (int n = 0; n < 4; ++n)
        acc[m][n] = __builtin_amdgcn_mfma_f32_16x16x32_bf16(af[m], bfr[n], acc[m][n], 0, 0, 0);
    if (++kt == NK) break;
    __syncthreads();
    cur ^= 1;
  }

  __syncthreads();   // staging retires; LDS repurposed (per-wave strips)

  const int row0 = mt * 128 + wr * 64, col0 = nt * 128 + wc * 64;
  float* es = lds.ep[w];
  #pragma unroll
  for (int p = 0; p < 2; ++p) {
    // write pass p: acc m = 2p, 2p+1 -> strip rows 0..31
    #pragma unroll
    for (int n = 0; n < 4; ++n) {
      const float bb = bias[col0 + n * 16 + (l & 15)];
      #pragma unroll
      for (int m2 = 0; m2 < 2; ++m2) {
        #pragma unroll
        for (int r = 0; r < 4; ++r) {
          float v = acc[p * 2 + m2][n][r] + bb;
          if (ACT) v = mishf(v);
          es[(m2 * 16 + ((l >> 4) << 2) + r) * 66 + n * 16 + (l & 15)] = v;
        }
      }
    }
    // read back (wave-private strip; in-order LDS + waitcnt gives visibility)
    const int rr = l >> 1, cc = (l & 1) * 32;
    const float* er = es + rr * 66 + cc;
    const int gr = row0 + p * 32 + rr, gc0 = col0 + cc;
    if (OUTBF) {
      __bf16* op = (__bf16*)Cv + (size_t)gr * N + gc0;
      #pragma unroll
      for (int c = 0; c < 4; ++c) {
        f4v a = *(const f4v*)(er + c * 8);
        f4v b = *(const f4v*)(er + c * 8 + 4);
        bf16x8 o;
        #pragma unroll
        for (int j = 0; j < 4; ++j) { o[j] = (__bf16)a[j]; o[4 + j] = (__bf16)b[j]; }
        *(bf16x8*)(op + c * 8) = o;
      }
    } else {
      float* op = (float*)Cv + (size_t)gr * N + gc0;
      const float* rp = RES ? res + (size_t)gr * N + gc0 : nullptr;
      #pragma unroll
      for (int c = 0; c < 8; ++c) {
        f4v v = *(const f4v*)(er + c * 4);
        if (RES) v += *(const f4v*)(rp + c * 4);
        *(f4v*)(op + c * 4) = v;
      }
    }
  }
}

// ---------------- flash attention over packed QKV [M][768] ----------------
// 1D grid 256, XCD-chunked so the 8 q-tiles of a bh share an XCD (K/V L2 reuse)
__global__ __launch_bounds__(512) void attn_fwd(
    const __bf16* __restrict__ QKV, __bf16* __restrict__ Om)
{
  __shared__ __bf16 Ks[2][32][256];   // K tile, XOR-swizzled rows
  __shared__ __bf16 Vs[2][256][32];   // V^T tile [n][k]
  __shared__ __bf16 Ps[8][16][32];    // per-wave P relayout buffer
  const int tid = threadIdx.x, l = tid & 63, w = tid >> 6;
  const int wgs = (blockIdx.x & 7) * 32 + (blockIdx.x >> 3);
  const int bh = wgs >> 3, qt = wgs & 7;
  const size_t rbase = (size_t)bh * 1024 * 768;   // bh row base in QKV
  const int qr0 = qt * 128 + w * 16;

  bf16x8 qf[8];
  {
    const __bf16* qp = QKV + rbase + (size_t)(qr0 + (l & 15)) * 768 + ((l >> 4) << 3);
    #pragma unroll
    for (int s = 0; s < 8; ++s) qf[s] = *(const bf16x8*)(qp + s * 32);
  }
  f32x4 acc[16] = {};
  float lacc[4] = {0.f, 0.f, 0.f, 0.f};

  const int kec = tid & 31, kr_ = tid >> 5;
  const int vp = tid & 15, vc = tid >> 4;
  const __bf16* gK = QKV + 256 + rbase + kec * 8;
  const __bf16* gV = QKV + 512 + rbase + vc * 8;

  uint4 rk0, rk1, rv0, rv1;
  auto ldKV = [&](int kt) {
    const __bf16* k0 = gK + (size_t)(kt * 32 + kr_) * 768;
    rk0 = *(const uint4*)k0;
    rk1 = *(const uint4*)(k0 + 16 * 768);
    const __bf16* v0 = gV + (size_t)(kt * 32 + vp * 2) * 768;
    rv0 = *(const uint4*)v0;
    rv1 = *(const uint4*)(v0 + 768);
  };
  auto wrKV = [&](int buf) {
    char* kb = (char*)&Ks[buf][0][0];
    const int a0 = (kr_ * 512 + kec * 16) ^ ((kr_ & 15) << 4);
    const int a1 = ((kr_ + 16) * 512 + kec * 16) ^ (((kr_ + 16) & 15) << 4);
    *(uint4*)(kb + a0) = rk0;
    *(uint4*)(kb + a1) = rk1;
    const ushort_t* s0 = (const ushort_t*)&rv0;
    const ushort_t* s1 = (const ushort_t*)&rv1;
    #pragma unroll
    for (int i = 0; i < 8; ++i) {
      unsigned pk = (unsigned)s0[i] | ((unsigned)s1[i] << 16);
      *(unsigned*)&Vs[buf][vc * 8 + i][vp * 2] = pk;
    }
  };

  ldKV(0); wrKV(0);
  __syncthreads();
  int cur = 0;
  for (int kt = 0;;) {
    if (kt + 1 < 32) ldKV(kt + 1);
    f32x4 S[2] = {};
    const char* kbase = (const char*)&Ks[cur][0][0];
    #pragma unroll
    for (int t = 0; t < 2; ++t) {
      const int kcol = t * 16 + (l & 15);
      const int swz = (kcol & 15) << 4;
      #pragma unroll
      for (int s = 0; s < 8; ++s) {
        uint4 kf = *(const uint4*)(kbase + ((kcol * 512 + s * 64 + ((l >> 4) << 4)) ^ swz));
        S[t] = __builtin_amdgcn_mfma_f32_16x16x32_bf16(qf[s], __builtin_bit_cast(bf16x8, kf), S[t], 0, 0, 0);
      }
    }
    #pragma unroll
    for (int t = 0; t < 2; ++t)
      #pragma unroll
      for (int r = 0; r < 4; ++r) {
        float p = __expf(S[t][r]);
        lacc[r] += p;
        Ps[w][((l >> 4) << 2) + r][t * 16 + (l & 15)] = (__bf16)p;
      }
    bf16x8 pf = *(const bf16x8*)&Ps[w][l & 15][(l >> 4) << 3];
    #pragma unroll
    for (int n = 0; n < 16; ++n) {
      uint4 vf = *(const uint4*)&Vs[cur][n * 16 + (l & 15)][(l >> 4) << 3];
      acc[n] = __builtin_amdgcn_mfma_f32_16x16x32_bf16(pf, __builtin_bit_cast(bf16x8, vf), acc[n], 0, 0, 0);
    }
    if (++kt == 32) break;
    wrKV(cur ^ 1);
    __syncthreads();
    cur ^= 1;
  }
  f32x4 inv;
  #pragma unroll
  for (int r = 0; r < 4; ++r) {
    float s = lacc[r];
    s += __shfl_xor(s, 1); s += __shfl_xor(s, 2);
    s += __shfl_xor(s, 4); s += __shfl_xor(s, 8);
    inv[r] = 1.f / (16.f * s);
  }
  __bf16* op = Om + (size_t)(bh * 1024 + qr0 + ((l >> 4) << 2)) * 256 + (l & 15);
  #pragma unroll
  for (int n = 0; n < 16; ++n)
    #pragma unroll
    for (int r = 0; r < 4; ++r)
      op[(size_t)r * 256 + n * 16] = (__bf16)(acc[n][r] * inv[r]);
}

// ---------------- host launch ----------------
extern "C" void kernel_launch(void* const* d_in, const int* in_sizes, int n_in,
                              void* d_out, int out_size, void* d_ws, size_t ws_size,
                              hipStream_t stream)
{
  const float* x    = (const float*)d_in[0];
  const float* ln1w = (const float*)d_in[1];
  const float* ln1b = (const float*)d_in[2];
  const float* Wq   = (const float*)d_in[3];
  const float* bq   = (const float*)d_in[4];
  const float* Wk   = (const float*)d_in[5];
  const float* bk   = (const float*)d_in[6];
  const float* Wv   = (const float*)d_in[7];
  const float* bv   = (const float*)d_in[8];
  const float* Wp   = (const float*)d_in[9];
  const float* bp   = (const float*)d_in[10];
  const float* ln2w = (const float*)d_in[11];
  const float* ln2b = (const float*)d_in[12];
  const float* W1   = (const float*)d_in[13];
  const float* b1   = (const float*)d_in[14];
  const float* W2   = (const float*)d_in[15];
  const float* b2   = (const float*)d_in[16];

  // ws layout (bytes), peak 136.3 MB:
  char* ws = (char*)d_ws;
  __bf16* wb   = (__bf16*)(ws);               // packed bf16 weights (1.5 MB)
  float*  bqkv = (float*)(ws + 1572864);      // packed qkv bias (3 KB)
  __bf16* y    = (__bf16*)(ws + 2097152);     // LN1 out / attn out (16 MB)
  __bf16* qkv  = (__bf16*)(ws + 18874368);    // packed QKV [M][768] (48 MB)
  float*  x1   = (float*)(ws + 18874368);     // residual fp32 (32 MB, aliases qkv lo)
  __bf16* hb   = (__bf16*)(ws + 52428800);    // LN2 out (16 MB, aliases qkv hi)
  __bf16* h1   = (__bf16*)(ws + 69206016);    // MLP hidden (64 MB)
  __bf16* ao   = y;
  float*  outp = (float*)d_out;

  castw<<<768, 256, 0, stream>>>(Wq, Wk, Wv, Wp, W1, W2, wb);
  packb<<<1, 768, 0, stream>>>(bq, bk, bv, bqkv);
  ln_rows<<<8192, 256, 0, stream>>>(x, ln1w, ln1b, y);
  gemm_bt<0,0,1><<<dim3(256, 6), 256, 0, stream>>>(y,  wb,          bqkv, nullptr, qkv,  768,  256);
  attn_fwd<<<256, 512, 0, stream>>>(qkv, ao);
  gemm_bt<0,1,0><<<dim3(256, 2), 256, 0, stream>>>(ao, wb + 196608, bp,   x,       x1,   256,  256);
  ln_rows<<<8192, 256, 0, stream>>>(x1, ln2w, ln2b, hb);
  gemm_bt<1,0,1><<<dim3(256, 8), 256, 0, stream>>>(hb, wb + 262144, b1,   nullptr, h1,  1024,  256);
  gemm_bt<1,1,0><<<dim3(256, 2), 256, 0, stream>>>(h1, wb + 524288, b2,   x1,      outp, 256, 1024);
}

// Round 7
// 225.516 us; speedup vs baseline: 1.5535x; 1.5535x over previous
//
#include <hip/hip_runtime.h>

typedef float  f32x4  __attribute__((ext_vector_type(4)));
typedef float  f4v    __attribute__((ext_vector_type(4)));
typedef __bf16 bf16x8 __attribute__((ext_vector_type(8)));
typedef __bf16 bf16x4 __attribute__((ext_vector_type(4)));
typedef unsigned short ushort_t;

#define AS1 __attribute__((address_space(1)))
#define AS3 __attribute__((address_space(3)))

static __device__ __forceinline__ void gload_lds16(const void* g, void* l) {
  __builtin_amdgcn_global_load_lds((const AS1 void*)g, (AS3 void*)l, 16, 0, 0);
}

template<int N> static __device__ __forceinline__ void vm_wait() {
  static_assert(N==0||N==3||N==4||N==6||N==8, "vmcnt literal");
  if constexpr (N==0)      asm volatile("s_waitcnt vmcnt(0)" ::: "memory");
  else if constexpr (N==3) asm volatile("s_waitcnt vmcnt(3)" ::: "memory");
  else if constexpr (N==4) asm volatile("s_waitcnt vmcnt(4)" ::: "memory");
  else if constexpr (N==6) asm volatile("s_waitcnt vmcnt(6)" ::: "memory");
  else                     asm volatile("s_waitcnt vmcnt(8)" ::: "memory");
}

// mish(x) = x * u/(u+2), u = t*(t+2), t = e^x; guard large x.
static __device__ __forceinline__ float mishf(float x) {
  float t = __expf(x);
  float u = t * (t + 2.f);
  float y = x * __fdividef(u, u + 2.f);
  return (x > 15.f) ? x : y;
}

// ---------------- weight cast fp32 -> bf16 (packed layout) ----------------
__global__ __launch_bounds__(256) void castw(
    const float* __restrict__ Wq, const float* __restrict__ Wk,
    const float* __restrict__ Wv, const float* __restrict__ Wp,
    const float* __restrict__ W1, const float* __restrict__ W2,
    __bf16* __restrict__ out)
{
  const int i = (blockIdx.x * 256 + threadIdx.x) * 4;
  const float* src; int off = i;
  if      (i < 65536)  { src = Wq; }
  else if (i < 131072) { src = Wk; off = i - 65536; }
  else if (i < 196608) { src = Wv; off = i - 131072; }
  else if (i < 262144) { src = Wp; off = i - 196608; }
  else if (i < 524288) { src = W1; off = i - 262144; }
  else                 { src = W2; off = i - 524288; }
  const f4v v = *(const f4v*)(src + off);
  bf16x4 o;
  #pragma unroll
  for (int j = 0; j < 4; ++j) o[j] = (__bf16)v[j];
  *(bf16x4*)(out + i) = o;
}

__global__ void packb(const float* __restrict__ a, const float* __restrict__ b,
                      const float* __restrict__ c, float* __restrict__ o) {
  int i = threadIdx.x;  // 768 threads
  o[i] = (i < 256) ? a[i] : (i < 512 ? b[i - 256] : c[i - 512]);
}

// ---------------- LayerNorm row kernel: fp32 in -> bf16 out ----------------
__global__ __launch_bounds__(256) void ln_rows(
    const float* __restrict__ X, const float* __restrict__ g,
    const float* __restrict__ b, __bf16* __restrict__ Y)
{
  const int l = threadIdx.x & 63;
  const size_t row = (size_t)blockIdx.x * 4 + (threadIdx.x >> 6);
  const f4v x = *(const f4v*)(X + row * 256 + l * 4);
  float s = x[0] + x[1] + x[2] + x[3];
  float q = x[0]*x[0] + x[1]*x[1] + x[2]*x[2] + x[3]*x[3];
  #pragma unroll
  for (int d = 1; d < 64; d <<= 1) { s += __shfl_xor(s, d); q += __shfl_xor(q, d); }
  const float mu = s * (1.f / 256.f);
  const float rs = rsqrtf(q * (1.f / 256.f) - mu * mu + 1e-5f);
  const f4v gv = *(const f4v*)(g + l * 4);
  const f4v bv = *(const f4v*)(b + l * 4);
  bf16x4 o;
  #pragma unroll
  for (int j = 0; j < 4; ++j) o[j] = (__bf16)((x[j] - mu) * rs * gv[j] + bv[j]);
  *(bf16x4*)(Y + row * 256 + l * 4) = o;
}

// ---------------- counted-vmcnt pipelined GEMM (T3+T4+T5) -----------------
// out[M][ldo](+nt*256 cols) = act(A[M][K] @ W[ncols][K]^T + bias) (+res)
// K = KT*32. Block 512 thr / 8 waves; tile BM x 256; wave BM/WR x 256/WC.
// 4-deep circular K-tile LDS (slot = t&3). Per K-tile: 2 phases x 16(or 8)
// MFMA; one 16KB granule staged per phase (A at ph0, B at ph1, for tile
// t+3). Checkpoint ONCE per K-tile: vmcnt(2*ST) steady (ST instrs/tile),
// ST at t==KT-3, 0 at t>=KT-2. Raw s_barrier (no vmcnt0 drain) +
// sched_barrier(0) pins at every barrier. Ledger (per wave, in-order
// retire): entering tile t, granules of t are retired; 3 granules in
// flight. Direct-store epilogue (no LDS).
template<int BM, int KT, int NTB, int ACT, int RES, int OUTBF>
__global__ __launch_bounds__(512, 2) void gemm8(
    const __bf16* __restrict__ A, const __bf16* __restrict__ Wg,
    const float* __restrict__ bias, const float* __restrict__ res,
    void* __restrict__ out, int ldo)
{
  constexpr int K  = KT * 32;
  constexpr int SA = BM / 128, SB = 2, ST = SA + SB;   // stage instrs per tile
  constexpr int WC = (BM == 256) ? 4 : 8;              // waves along N
  constexpr int CF = 256 / (16 * WC);                  // col frags per wave
  __shared__ __bf16 lds[4][(BM + 256) * 32];

  const int tid = threadIdx.x, l = tid & 63, w = tid >> 6;
  const int wr = w / WC, wc = w % WC;
  const int nwg = gridDim.x;
  const int wg = (blockIdx.x & 7) * (nwg >> 3) + (blockIdx.x >> 3);
  const int mt = wg / NTB, nt = wg % NTB;
  const int row0 = mt * BM, col0 = nt * 256;

  auto stageA = [&](int t) {
    #pragma unroll
    for (int j = 0; j < SA; ++j) {
      const int s = j * 512 + tid, r = s >> 2, u = s & 3;
      gload_lds16(A + (size_t)(row0 + r) * K + t * 32 + u * 8, &lds[t & 3][s << 3]);
    }
  };
  auto stageB = [&](int t) {
    #pragma unroll
    for (int j = 0; j < SB; ++j) {
      const int s = j * 512 + tid, r = s >> 2, u = s & 3;
      gload_lds16(Wg + (size_t)(col0 + r) * K + t * 32 + u * 8,
                  &lds[t & 3][BM * 32 + (s << 3)]);
    }
  };

  f32x4 acc[8][CF] = {};

  // prologue: tiles 0,1,2 issued; retire tile 0 (keep 2 tiles = 2*ST in flight)
  stageA(0); stageB(0); stageA(1); stageB(1); stageA(2); stageB(2);
  vm_wait<2 * ST>();
  __builtin_amdgcn_s_barrier();
  __builtin_amdgcn_sched_barrier(0);

  for (int t = 0;;) {
    const __bf16* La = &lds[t & 3][0];
    const __bf16* Lb = &lds[t & 3][BM * 32];
    #pragma unroll
    for (int ph = 0; ph < 2; ++ph) {
      bf16x8 af[4], bf[CF];
      #pragma unroll
      for (int m = 0; m < 4; ++m) {
        const int r = wr * 128 + (ph * 4 + m) * 16 + (l & 15);
        af[m] = *(const bf16x8*)&La[((r << 2) | (l >> 4)) << 3];
      }
      #pragma unroll
      for (int n = 0; n < CF; ++n) {
        const int r = wc * (CF * 16) + n * 16 + (l & 15);
        bf[n] = *(const bf16x8*)&Lb[((r << 2) | (l >> 4)) << 3];
      }
      if (t + 3 < KT) { if (ph == 0) stageA(t + 3); else stageB(t + 3); }
      __builtin_amdgcn_s_barrier();
      __builtin_amdgcn_sched_barrier(0);
      __builtin_amdgcn_s_setprio(1);
      #pragma unroll
      for (int m = 0; m < 4; ++m)
        #pragma unroll
        for (int n = 0; n < CF; ++n)
          acc[ph * 4 + m][n] =
              __builtin_amdgcn_mfma_f32_16x16x32_bf16(af[m], bf[n], acc[ph * 4 + m][n], 0, 0, 0);
      __builtin_amdgcn_s_setprio(0);
      if (ph == 1) {                       // per-K-tile checkpoint (counted!)
        const int rem = KT - t - 2;
        if (rem >= 2)      vm_wait<2 * ST>();
        else if (rem == 1) vm_wait<ST>();
        else               vm_wait<0>();
      }
      __builtin_amdgcn_s_barrier();
      __builtin_amdgcn_sched_barrier(0);
    }
    if (++t == KT) break;
  }

  // ---------------- epilogue: direct global stores ----------------
  #pragma unroll
  for (int n = 0; n < CF; ++n) {
    const int col = col0 + wc * (CF * 16) + n * 16 + (l & 15);
    const float bb = bias[col];
    #pragma unroll
    for (int m = 0; m < 8; ++m) {
      const int row = row0 + wr * 128 + m * 16 + ((l >> 4) << 2);
      #pragma unroll
      for (int r = 0; r < 4; ++r) {
        float v = acc[m][n][r] + bb;
        if (ACT) v = mishf(v);
        if (OUTBF) {
          ((__bf16*)out)[(size_t)(row + r) * ldo + col] = (__bf16)v;
        } else {
          if (RES) v += res[(size_t)(row + r) * ldo + col];
          ((float*)out)[(size_t)(row + r) * ldo + col] = v;
        }
      }
    }
  }
}

// ---------------- flash attention over packed QKV [M][768] ----------------
// 1D grid 256, XCD-chunked so the 8 q-tiles of a bh share an XCD (K/V L2 reuse)
__global__ __launch_bounds__(512) void attn_fwd(
    const __bf16* __restrict__ QKV, __bf16* __restrict__ Om)
{
  __shared__ __bf16 Ks[2][32][256];   // K tile, XOR-swizzled rows
  __shared__ __bf16 Vs[2][256][32];   // V^T tile [n][k]
  __shared__ __bf16 Ps[8][16][32];    // per-wave P relayout buffer
  const int tid = threadIdx.x, l = tid & 63, w = tid >> 6;
  const int wgs = (blockIdx.x & 7) * 32 + (blockIdx.x >> 3);
  const int bh = wgs >> 3, qt = wgs & 7;
  const size_t rbase = (size_t)bh * 1024 * 768;   // bh row base in QKV
  const int qr0 = qt * 128 + w * 16;

  bf16x8 qf[8];
  {
    const __bf16* qp = QKV + rbase + (size_t)(qr0 + (l & 15)) * 768 + ((l >> 4) << 3);
    #pragma unroll
    for (int s = 0; s < 8; ++s) qf[s] = *(const bf16x8*)(qp + s * 32);
  }
  f32x4 acc[16] = {};
  float lacc[4] = {0.f, 0.f, 0.f, 0.f};

  const int kec = tid & 31, kr_ = tid >> 5;
  const int vp = tid & 15, vc = tid >> 4;
  const __bf16* gK = QKV + 256 + rbase + kec * 8;
  const __bf16* gV = QKV + 512 + rbase + vc * 8;

  uint4 rk0, rk1, rv0, rv1;
  auto ldKV = [&](int kt) {
    const __bf16* k0 = gK + (size_t)(kt * 32 + kr_) * 768;
    rk0 = *(const uint4*)k0;
    rk1 = *(const uint4*)(k0 + 16 * 768);
    const __bf16* v0 = gV + (size_t)(kt * 32 + vp * 2) * 768;
    rv0 = *(const uint4*)v0;
    rv1 = *(const uint4*)(v0 + 768);
  };
  auto wrKV = [&](int buf) {
    char* kb = (char*)&Ks[buf][0][0];
    const int a0 = (kr_ * 512 + kec * 16) ^ ((kr_ & 15) << 4);
    const int a1 = ((kr_ + 16) * 512 + kec * 16) ^ (((kr_ + 16) & 15) << 4);
    *(uint4*)(kb + a0) = rk0;
    *(uint4*)(kb + a1) = rk1;
    const ushort_t* s0 = (const ushort_t*)&rv0;
    const ushort_t* s1 = (const ushort_t*)&rv1;
    #pragma unroll
    for (int i = 0; i < 8; ++i) {
      unsigned pk = (unsigned)s0[i] | ((unsigned)s1[i] << 16);
      *(unsigned*)&Vs[buf][vc * 8 + i][vp * 2] = pk;
    }
  };

  ldKV(0); wrKV(0);
  __syncthreads();
  int cur = 0;
  for (int kt = 0;;) {
    if (kt + 1 < 32) ldKV(kt + 1);
    f32x4 S[2] = {};
    const char* kbase = (const char*)&Ks[cur][0][0];
    #pragma unroll
    for (int t = 0; t < 2; ++t) {
      const int kcol = t * 16 + (l & 15);
      const int swz = (kcol & 15) << 4;
      #pragma unroll
      for (int s = 0; s < 8; ++s) {
        uint4 kf = *(const uint4*)(kbase + ((kcol * 512 + s * 64 + ((l >> 4) << 4)) ^ swz));
        S[t] = __builtin_amdgcn_mfma_f32_16x16x32_bf16(qf[s], __builtin_bit_cast(bf16x8, kf), S[t], 0, 0, 0);
      }
    }
    #pragma unroll
    for (int t = 0; t < 2; ++t)
      #pragma unroll
      for (int r = 0; r < 4; ++r) {
        float p = __expf(S[t][r]);
        lacc[r] += p;
        Ps[w][((l >> 4) << 2) + r][t * 16 + (l & 15)] = (__bf16)p;
      }
    bf16x8 pf = *(const bf16x8*)&Ps[w][l & 15][(l >> 4) << 3];
    #pragma unroll
    for (int n = 0; n < 16; ++n) {
      uint4 vf = *(const uint4*)&Vs[cur][n * 16 + (l & 15)][(l >> 4) << 3];
      acc[n] = __builtin_amdgcn_mfma_f32_16x16x32_bf16(pf, __builtin_bit_cast(bf16x8, vf), acc[n], 0, 0, 0);
    }
    if (++kt == 32) break;
    wrKV(cur ^ 1);
    __syncthreads();
    cur ^= 1;
  }
  f32x4 inv;
  #pragma unroll
  for (int r = 0; r < 4; ++r) {
    float s = lacc[r];
    s += __shfl_xor(s, 1); s += __shfl_xor(s, 2);
    s += __shfl_xor(s, 4); s += __shfl_xor(s, 8);
    inv[r] = 1.f / (16.f * s);
  }
  __bf16* op = Om + (size_t)(bh * 1024 + qr0 + ((l >> 4) << 2)) * 256 + (l & 15);
  #pragma unroll
  for (int n = 0; n < 16; ++n)
    #pragma unroll
    for (int r = 0; r < 4; ++r)
      op[(size_t)r * 256 + n * 16] = (__bf16)(acc[n][r] * inv[r]);
}

// ---------------- host launch ----------------
extern "C" void kernel_launch(void* const* d_in, const int* in_sizes, int n_in,
                              void* d_out, int out_size, void* d_ws, size_t ws_size,
                              hipStream_t stream)
{
  const float* x    = (const float*)d_in[0];
  const float* ln1w = (const float*)d_in[1];
  const float* ln1b = (const float*)d_in[2];
  const float* Wq   = (const float*)d_in[3];
  const float* bq   = (const float*)d_in[4];
  const float* Wk   = (const float*)d_in[5];
  const float* bk   = (const float*)d_in[6];
  const float* Wv   = (const float*)d_in[7];
  const float* bv   = (const float*)d_in[8];
  const float* Wp   = (const float*)d_in[9];
  const float* bp   = (const float*)d_in[10];
  const float* ln2w = (const float*)d_in[11];
  const float* ln2b = (const float*)d_in[12];
  const float* W1   = (const float*)d_in[13];
  const float* b1   = (const float*)d_in[14];
  const float* W2   = (const float*)d_in[15];
  const float* b2   = (const float*)d_in[16];

  // ws layout (bytes), peak 136.3 MB:
  char* ws = (char*)d_ws;
  __bf16* wb   = (__bf16*)(ws);               // packed bf16 weights (1.5 MB)
  float*  bqkv = (float*)(ws + 1572864);      // packed qkv bias (3 KB)
  __bf16* y    = (__bf16*)(ws + 2097152);     // LN1 out / attn out (16 MB)
  __bf16* qkv  = (__bf16*)(ws + 18874368);    // packed QKV [M][768] (48 MB)
  float*  x1   = (float*)(ws + 18874368);     // residual fp32 (32 MB, aliases qkv lo)
  __bf16* hb   = (__bf16*)(ws + 52428800);    // LN2 out (16 MB, aliases qkv hi)
  __bf16* h1   = (__bf16*)(ws + 69206016);    // MLP hidden (64 MB)
  __bf16* ao   = y;
  float*  outp = (float*)d_out;

  castw<<<768, 256, 0, stream>>>(Wq, Wk, Wv, Wp, W1, W2, wb);
  packb<<<1, 768, 0, stream>>>(bq, bk, bv, bqkv);
  ln_rows<<<8192, 256, 0, stream>>>(x, ln1w, ln1b, y);
  // QKV: [32768][256] @ [768][256]^T -> [32768][768]
  gemm8<256, 8, 3, 0, 0, 1><<<384, 512, 0, stream>>>(y,  wb,          bqkv, nullptr, qkv,  768);
  attn_fwd<<<256, 512, 0, stream>>>(qkv, ao);
  // proj: +x residual, fp32 out
  gemm8<128, 8, 1, 0, 1, 0><<<256, 512, 0, stream>>>(ao, wb + 196608, bp,   x,       x1,   256);
  ln_rows<<<8192, 256, 0, stream>>>(x1, ln2w, ln2b, hb);
  // MLP1: mish, bf16 out [32768][1024]
  gemm8<256, 8, 4, 1, 0, 1><<<512, 512, 0, stream>>>(hb, wb + 262144, b1,   nullptr, h1,  1024);
  // MLP2: K=1024, mish + x1 residual, fp32 out
  gemm8<128, 32, 1, 1, 1, 0><<<256, 512, 0, stream>>>(h1, wb + 524288, b2,  x1,      outp, 256);
}